// Round 3
// baseline (3818.888 us; speedup 1.0000x reference)
//
#include <hip/hip_runtime.h>
#include <math.h>

#define B_ 2
#define N_ 2048
#define IN_DIM_ 256
#define DIM_ 256
#define H_ 8
#define DH_ 32
#define TOPK_ 4
#define EPS_ 1e-5f
#define TEMP_ 0.17677669529663687f  // 1/sqrt(32)

// ---------------- LayerNorm: one row (256 floats) per 64-lane wave ----------------
__global__ __launch_bounds__(256) void ln_kernel(const float* __restrict__ x,
                                                 const float* __restrict__ gamma,
                                                 const float* __restrict__ beta,
                                                 float* __restrict__ xn) {
  int w = threadIdx.x >> 6, ld = threadIdx.x & 63;
  int row = blockIdx.x * 4 + w;
  const float4* xr = (const float4*)(x + (size_t)row * 256);
  float4 v = xr[ld];
  float s = v.x + v.y + v.z + v.w;
  float ss = v.x * v.x + v.y * v.y + v.z * v.z + v.w * v.w;
  #pragma unroll
  for (int off = 1; off < 64; off <<= 1) {
    s += __shfl_xor(s, off);
    ss += __shfl_xor(ss, off);
  }
  float mu = s * (1.0f / 256.0f);
  float var = ss * (1.0f / 256.0f) - mu * mu;
  float rstd = rsqrtf(var + EPS_);
  float4 g = ((const float4*)gamma)[ld];
  float4 bt = ((const float4*)beta)[ld];
  float4 o;
  o.x = (v.x - mu) * rstd * g.x + bt.x;
  o.y = (v.y - mu) * rstd * g.y + bt.y;
  o.z = (v.z - mu) * rstd * g.z + bt.z;
  o.w = (v.w - mu) * rstd * g.w + bt.w;
  ((float4*)(xn + (size_t)row * 256))[ld] = o;
}

// ---------------- fp32 tiled GEMM: C[m][n] = sum_k A[m*K+k] * Bm[n*K+k] ----------------
template <bool PROJ>
__global__ __launch_bounds__(256) void gemm_nt(const float* __restrict__ A,
                                               const float* __restrict__ Bm,
                                               float* __restrict__ C,
                                               const float* __restrict__ vres,
                                               const float* __restrict__ bias,
                                               int K, int ldc) {
  __shared__ float As[32][64];
  __shared__ float Bs[32][64];
  int m0 = blockIdx.x * 64, n0 = blockIdx.y * 64;
  int t = threadIdx.x;
  int tm = t & 15, tn = t >> 4;
  float acc[4][4] = {};
  for (int k0 = 0; k0 < K; k0 += 32) {
    __syncthreads();
    for (int f = t; f < 512; f += 256) {
      int row = f >> 3, j = f & 7;
      float4 a = *(const float4*)(A + (size_t)(m0 + row) * K + k0 + j * 4);
      As[j * 4 + 0][row] = a.x; As[j * 4 + 1][row] = a.y;
      As[j * 4 + 2][row] = a.z; As[j * 4 + 3][row] = a.w;
      float4 b = *(const float4*)(Bm + (size_t)(n0 + row) * K + k0 + j * 4);
      Bs[j * 4 + 0][row] = b.x; Bs[j * 4 + 1][row] = b.y;
      Bs[j * 4 + 2][row] = b.z; Bs[j * 4 + 3][row] = b.w;
    }
    __syncthreads();
    #pragma unroll
    for (int k = 0; k < 32; k++) {
      float4 a = *(const float4*)&As[k][tm * 4];
      float4 b = *(const float4*)&Bs[k][tn * 4];
      float av[4] = {a.x, a.y, a.z, a.w};
      float bv[4] = {b.x, b.y, b.z, b.w};
      #pragma unroll
      for (int i = 0; i < 4; i++)
        #pragma unroll
        for (int j = 0; j < 4; j++)
          acc[i][j] = fmaf(av[i], bv[j], acc[i][j]);
    }
  }
  #pragma unroll
  for (int i = 0; i < 4; i++) {
    int m = m0 + tm * 4 + i;
    int n = n0 + tn * 4;
    float4 r = {acc[i][0], acc[i][1], acc[i][2], acc[i][3]};
    if (PROJ) {
      float4 vr = *(const float4*)(vres + (size_t)m * 768 + n);
      float4 bb = *(const float4*)(bias + n);
      r.x += vr.x + bb.x; r.y += vr.y + bb.y;
      r.z += vr.z + bb.z; r.w += vr.w + bb.w;
    }
    *(float4*)(C + (size_t)m * ldc + n) = r;
  }
}

// Branch-free sorted-top4 insert. ALL indices constant after inlining -> stays in
// registers (the R2 spill came from a dynamic-pos while-loop + o[qc] select).
__device__ __forceinline__ void ins4(float s, int idx, float tv[4], int ti[4]) {
  bool b0 = (s > tv[0]) || (s == tv[0] && idx < ti[0]);
  bool b1 = (s > tv[1]) || (s == tv[1] && idx < ti[1]);
  bool b2 = (s > tv[2]) || (s == tv[2] && idx < ti[2]);
  bool b3 = (s > tv[3]) || (s == tv[3] && idx < ti[3]);
  tv[3] = b2 ? tv[2] : (b3 ? s : tv[3]); ti[3] = b2 ? ti[2] : (b3 ? idx : ti[3]);
  tv[2] = b1 ? tv[1] : (b2 ? s : tv[2]); ti[2] = b1 ? ti[1] : (b2 ? idx : ti[2]);
  tv[1] = b0 ? tv[0] : (b1 ? s : tv[1]); ti[1] = b0 ? ti[0] : (b1 ? idx : ti[1]);
  tv[0] = b0 ? s : tv[0];                ti[0] = b0 ? idx : ti[0];
}

// ---------------- Flash attention + top-4, 2 query rows per lane ----------------
// Grid (N/64, H, B) = 512 blocks, 256 threads. Thread t: qr=t>>3 handles rows
// l0+qr and l0+qr+32; qc=t&7 owns s-columns qc*8..qc*8+7 of each 64-key tile.
// No online max (logits are ~N(0,1); max over 13M samples ~5.5 -> exp safe).
// Each Ks/Vs LDS read feeds BOTH rows (halves the LDS-instruction wall vs R1/R2).
__global__ __launch_bounds__(256, 2) void attn_kernel(const float* __restrict__ qkv,
                                                      float* __restrict__ msg,
                                                      float* __restrict__ out_s,
                                                      float* __restrict__ out_i) {
  const int l0 = blockIdx.x * 64;
  const int h = blockIdx.y;
  const int b = blockIdx.z;
  const int t = threadIdx.x;
  const int qr = t >> 3, qc = t & 7;

  // chunk c of key-row ss stored at col (c + (ss>>3)) & 7 -> the 8 qc lanes hit
  // 8 distinct bank-quads (conflict-free); 8 qr groups broadcast (free).
  __shared__ float4 Ks[64][8];
  __shared__ float4 Vs[64][8];

  const size_t rs = 768;  // qkv row stride
  const float* qrow0 = qkv + ((size_t)(b * N_) + l0 + qr) * rs + h * DH_;
  const float* qrow1 = qrow0 + 32 * rs;
  float4 qa[8], qb[8];
  #pragma unroll
  for (int c = 0; c < 8; c++) {
    float4 v0 = ((const float4*)qrow0)[c];
    v0.x *= TEMP_; v0.y *= TEMP_; v0.z *= TEMP_; v0.w *= TEMP_;
    qa[c] = v0;
    float4 v1 = ((const float4*)qrow1)[c];
    v1.x *= TEMP_; v1.y *= TEMP_; v1.z *= TEMP_; v1.w *= TEMP_;
    qb[c] = v1;
  }
  float4 oa[8], ob[8];
  #pragma unroll
  for (int c = 0; c < 8; c++) {
    oa[c] = make_float4(0.f, 0.f, 0.f, 0.f);
    ob[c] = make_float4(0.f, 0.f, 0.f, 0.f);
  }
  float la = 0.f, lb = 0.f;
  float tva[4], tvb[4];
  int tia[4], tib[4];
  #pragma unroll
  for (int i = 0; i < 4; i++) {
    tva[i] = -INFINITY; tia[i] = 0x7fffffff;
    tvb[i] = -INFINITY; tib[i] = 0x7fffffff;
  }

  const float* kbase = qkv + (size_t)(b * N_) * rs + 256 + h * DH_;

  for (int s0 = 0; s0 < N_; s0 += 64) {
    __syncthreads();
    #pragma unroll
    for (int f0 = 0; f0 < 512; f0 += 256) {
      int f = f0 + t;
      int row = f >> 3, j = f & 7;
      int col = (j + (row >> 3)) & 7;
      const float* kp = kbase + (size_t)(s0 + row) * rs + j * 4;
      Ks[row][col] = *(const float4*)kp;
      Vs[row][col] = *(const float4*)(kp + 256);
    }
    __syncthreads();

    #pragma unroll
    for (int j = 0; j < 8; j++) {
      int ss = qc * 8 + j;
      float4 aa = {0, 0, 0, 0}, ab = {0, 0, 0, 0};
      #pragma unroll
      for (int c = 0; c < 8; c++) {
        float4 kv = Ks[ss][(c + qc) & 7];
        float4 q0 = qa[c];
        float4 q1 = qb[c];
        aa.x = fmaf(q0.x, kv.x, aa.x); aa.y = fmaf(q0.y, kv.y, aa.y);
        aa.z = fmaf(q0.z, kv.z, aa.z); aa.w = fmaf(q0.w, kv.w, aa.w);
        ab.x = fmaf(q1.x, kv.x, ab.x); ab.y = fmaf(q1.y, kv.y, ab.y);
        ab.z = fmaf(q1.z, kv.z, ab.z); ab.w = fmaf(q1.w, kv.w, ab.w);
      }
      float sa = (aa.x + aa.y) + (aa.z + aa.w);
      float sb = (ab.x + ab.y) + (ab.z + ab.w);
      int idx = s0 + ss;
      ins4(sa, idx, tva, tia);
      ins4(sb, idx, tvb, tib);
      float pa = __expf(sa);
      float pb = __expf(sb);
      la += pa;
      lb += pb;
      #pragma unroll
      for (int c = 0; c < 8; c++) {
        float4 vv = Vs[ss][(c + qc) & 7];
        oa[c].x = fmaf(pa, vv.x, oa[c].x); oa[c].y = fmaf(pa, vv.y, oa[c].y);
        oa[c].z = fmaf(pa, vv.z, oa[c].z); oa[c].w = fmaf(pa, vv.w, oa[c].w);
        ob[c].x = fmaf(pb, vv.x, ob[c].x); ob[c].y = fmaf(pb, vv.y, ob[c].y);
        ob[c].z = fmaf(pb, vv.z, ob[c].z); ob[c].w = fmaf(pb, vv.w, ob[c].w);
      }
    }
  }

  // ---- merge the 8 lanes of each query row (lanes contiguous: xor 1,2,4) ----
  la += __shfl_xor(la, 1); la += __shfl_xor(la, 2); la += __shfl_xor(la, 4);
  lb += __shfl_xor(lb, 1); lb += __shfl_xor(lb, 2); lb += __shfl_xor(lb, 4);
  #pragma unroll
  for (int d = 1; d <= 4; d <<= 1) {
    float ova[4], ovb[4];
    int oia[4], oib[4];
    #pragma unroll
    for (int r = 0; r < 4; r++) {
      ova[r] = __shfl_xor(tva[r], d); oia[r] = __shfl_xor(tia[r], d);
      ovb[r] = __shfl_xor(tvb[r], d); oib[r] = __shfl_xor(tib[r], d);
    }
    #pragma unroll
    for (int r = 0; r < 4; r++) {
      ins4(ova[r], oia[r], tva, tia);
      ins4(ovb[r], oib[r], tvb, tib);
    }
  }

  // ---- allreduce each O chunk across the 8 lanes; keep own chunk via cndmask ----
  float4 ra = {0, 0, 0, 0}, rb = {0, 0, 0, 0};
  #pragma unroll
  for (int c = 0; c < 8; c++) {
    float4 sa = oa[c], sb = ob[c];
    #pragma unroll
    for (int d = 1; d <= 4; d <<= 1) {
      sa.x += __shfl_xor(sa.x, d); sa.y += __shfl_xor(sa.y, d);
      sa.z += __shfl_xor(sa.z, d); sa.w += __shfl_xor(sa.w, d);
      sb.x += __shfl_xor(sb.x, d); sb.y += __shfl_xor(sb.y, d);
      sb.z += __shfl_xor(sb.z, d); sb.w += __shfl_xor(sb.w, d);
    }
    bool mine = (qc == c);
    ra.x = mine ? sa.x : ra.x; ra.y = mine ? sa.y : ra.y;
    ra.z = mine ? sa.z : ra.z; ra.w = mine ? sa.w : ra.w;
    rb.x = mine ? sb.x : rb.x; rb.y = mine ? sb.y : rb.y;
    rb.z = mine ? sb.z : rb.z; rb.w = mine ? sb.w : rb.w;
  }

  float linva = 1.0f / la, linvb = 1.0f / lb;
  ra.x *= linva; ra.y *= linva; ra.z *= linva; ra.w *= linva;
  rb.x *= linvb; rb.y *= linvb; rb.z *= linvb; rb.w *= linvb;

  float sca[4], scb[4];
  #pragma unroll
  for (int r = 0; r < 4; r++) {
    sca[r] = __expf(tva[r]) * linva;
    scb[r] = __expf(tvb[r]) * linvb;
    const float* vpa =
        qkv + ((size_t)(b * N_) + tia[r]) * rs + 512 + h * DH_ + qc * 4;
    float4 va = *(const float4*)vpa;
    ra.x = fmaf(-sca[r], va.x, ra.x); ra.y = fmaf(-sca[r], va.y, ra.y);
    ra.z = fmaf(-sca[r], va.z, ra.z); ra.w = fmaf(-sca[r], va.w, ra.w);
    const float* vpb =
        qkv + ((size_t)(b * N_) + tib[r]) * rs + 512 + h * DH_ + qc * 4;
    float4 vb = *(const float4*)vpb;
    rb.x = fmaf(-scb[r], vb.x, rb.x); rb.y = fmaf(-scb[r], vb.y, rb.y);
    rb.z = fmaf(-scb[r], vb.z, rb.z); rb.w = fmaf(-scb[r], vb.w, rb.w);
  }

  float* mpa = msg + ((size_t)(b * N_) + l0 + qr) * DIM_ + h * DH_ + qc * 4;
  *(float4*)mpa = ra;
  float* mpb = mpa + 32 * DIM_;
  *(float4*)mpb = rb;

  if (qc == 0) {
    size_t basea = ((size_t)(b * N_ + l0 + qr)) * TOPK_;
    size_t baseb = basea + 32 * TOPK_;
    #pragma unroll
    for (int r = 0; r < 4; r++) {
      out_s[(basea + r) * H_ + h] = sca[r];
      out_i[(basea + r) * H_ + h] = (float)tia[r];
      out_s[(baseb + r) * H_ + h] = scb[r];
      out_i[(baseb + r) * H_ + h] = (float)tib[r];
    }
  }
}

extern "C" void kernel_launch(void* const* d_in, const int* in_sizes, int n_in,
                              void* d_out, int out_size, void* d_ws, size_t ws_size,
                              hipStream_t stream) {
  const float* points = (const float*)d_in[0];
  const float* norm_gamma = (const float*)d_in[1];
  const float* norm_beta = (const float*)d_in[2];
  const float* w_qkv = (const float*)d_in[3];
  const float* w_proj = (const float*)d_in[4];
  const float* b_proj = (const float*)d_in[5];

  float* out0 = (float*)d_out;                       // message_flat (4096*256)
  float* out1 = out0 + (size_t)4096 * 256;           // topk_score (4096*4*8)
  float* out2 = out1 + (size_t)4096 * 4 * 8;         // topk_idx as float

  float* xn = (float*)d_ws;                          // 4096*256
  float* qkv = xn + (size_t)4096 * 256;              // 4096*768
  float* msg = qkv + (size_t)4096 * 768;             // 4096*256

  ln_kernel<<<1024, 256, 0, stream>>>(points, norm_gamma, norm_beta, xn);
  gemm_nt<false><<<dim3(64, 12), 256, 0, stream>>>(xn, w_qkv, qkv, nullptr,
                                                   nullptr, 256, 768);
  attn_kernel<<<dim3(N_ / 64, H_, B_), 256, 0, stream>>>(qkv, msg, out1, out2);
  gemm_nt<true><<<dim3(64, 4), 256, 0, stream>>>(msg, w_proj, out0, qkv + 512,
                                                 b_proj, 256, 256);
}

// Round 4
// 560.350 us; speedup vs baseline: 6.8152x; 6.8152x over previous
//
#include <hip/hip_runtime.h>
#include <math.h>

#define B_ 2
#define N_ 2048
#define IN_DIM_ 256
#define DIM_ 256
#define H_ 8
#define DH_ 32
#define TOPK_ 4
#define EPS_ 1e-5f
#define TEMP_ 0.17677669529663687f  // 1/sqrt(32)

// ---------------- LayerNorm: one row (256 floats) per 64-lane wave ----------------
__global__ __launch_bounds__(256) void ln_kernel(const float* __restrict__ x,
                                                 const float* __restrict__ gamma,
                                                 const float* __restrict__ beta,
                                                 float* __restrict__ xn) {
  int w = threadIdx.x >> 6, ld = threadIdx.x & 63;
  int row = blockIdx.x * 4 + w;
  const float4* xr = (const float4*)(x + (size_t)row * 256);
  float4 v = xr[ld];
  float s = v.x + v.y + v.z + v.w;
  float ss = v.x * v.x + v.y * v.y + v.z * v.z + v.w * v.w;
  #pragma unroll
  for (int off = 1; off < 64; off <<= 1) {
    s += __shfl_xor(s, off);
    ss += __shfl_xor(ss, off);
  }
  float mu = s * (1.0f / 256.0f);
  float var = ss * (1.0f / 256.0f) - mu * mu;
  float rstd = rsqrtf(var + EPS_);
  float4 g = ((const float4*)gamma)[ld];
  float4 bt = ((const float4*)beta)[ld];
  float4 o;
  o.x = (v.x - mu) * rstd * g.x + bt.x;
  o.y = (v.y - mu) * rstd * g.y + bt.y;
  o.z = (v.z - mu) * rstd * g.z + bt.z;
  o.w = (v.w - mu) * rstd * g.w + bt.w;
  ((float4*)(xn + (size_t)row * 256))[ld] = o;
}

// ---------------- fp32 tiled GEMM: C[m][n] = sum_k A[m*K+k] * Bm[n*K+k] ----------------
template <bool PROJ>
__global__ __launch_bounds__(256) void gemm_nt(const float* __restrict__ A,
                                               const float* __restrict__ Bm,
                                               float* __restrict__ C,
                                               const float* __restrict__ vres,
                                               const float* __restrict__ bias,
                                               int K, int ldc) {
  __shared__ float As[32][64];
  __shared__ float Bs[32][64];
  int m0 = blockIdx.x * 64, n0 = blockIdx.y * 64;
  int t = threadIdx.x;
  int tm = t & 15, tn = t >> 4;
  float acc[4][4] = {};
  for (int k0 = 0; k0 < K; k0 += 32) {
    __syncthreads();
    for (int f = t; f < 512; f += 256) {
      int row = f >> 3, j = f & 7;
      float4 a = *(const float4*)(A + (size_t)(m0 + row) * K + k0 + j * 4);
      As[j * 4 + 0][row] = a.x; As[j * 4 + 1][row] = a.y;
      As[j * 4 + 2][row] = a.z; As[j * 4 + 3][row] = a.w;
      float4 b = *(const float4*)(Bm + (size_t)(n0 + row) * K + k0 + j * 4);
      Bs[j * 4 + 0][row] = b.x; Bs[j * 4 + 1][row] = b.y;
      Bs[j * 4 + 2][row] = b.z; Bs[j * 4 + 3][row] = b.w;
    }
    __syncthreads();
    #pragma unroll
    for (int k = 0; k < 32; k++) {
      float4 a = *(const float4*)&As[k][tm * 4];
      float4 b = *(const float4*)&Bs[k][tn * 4];
      float av[4] = {a.x, a.y, a.z, a.w};
      float bv[4] = {b.x, b.y, b.z, b.w};
      #pragma unroll
      for (int i = 0; i < 4; i++)
        #pragma unroll
        for (int j = 0; j < 4; j++)
          acc[i][j] = fmaf(av[i], bv[j], acc[i][j]);
    }
  }
  #pragma unroll
  for (int i = 0; i < 4; i++) {
    int m = m0 + tm * 4 + i;
    int n = n0 + tn * 4;
    float4 r = {acc[i][0], acc[i][1], acc[i][2], acc[i][3]};
    if (PROJ) {
      float4 vr = *(const float4*)(vres + (size_t)m * 768 + n);
      float4 bb = *(const float4*)(bias + n);
      r.x += vr.x + bb.x; r.y += vr.y + bb.y;
      r.z += vr.z + bb.z; r.w += vr.w + bb.w;
    }
    *(float4*)(C + (size_t)m * ldc + n) = r;
  }
}

// Branch-free sorted-top4 insert, strict > only (constant indices -> registers).
// Scan order is ascending idx, so on a tie the incumbent (lower idx) wins -> matches
// lax.top_k. Use ins4_tie for merging lists that aren't in index order.
__device__ __forceinline__ void ins4(float s, int idx, float tv[4], int ti[4]) {
  bool b0 = s > tv[0];
  bool b1 = s > tv[1];
  bool b2 = s > tv[2];
  bool b3 = s > tv[3];
  tv[3] = b2 ? tv[2] : (b3 ? s : tv[3]); ti[3] = b2 ? ti[2] : (b3 ? idx : ti[3]);
  tv[2] = b1 ? tv[1] : (b2 ? s : tv[2]); ti[2] = b1 ? ti[1] : (b2 ? idx : ti[2]);
  tv[1] = b0 ? tv[0] : (b1 ? s : tv[1]); ti[1] = b0 ? ti[0] : (b1 ? idx : ti[1]);
  tv[0] = b0 ? s : tv[0];                ti[0] = b0 ? idx : ti[0];
}

__device__ __forceinline__ void ins4_tie(float s, int idx, float tv[4], int ti[4]) {
  bool b0 = (s > tv[0]) || (s == tv[0] && idx < ti[0]);
  bool b1 = (s > tv[1]) || (s == tv[1] && idx < ti[1]);
  bool b2 = (s > tv[2]) || (s == tv[2] && idx < ti[2]);
  bool b3 = (s > tv[3]) || (s == tv[3] && idx < ti[3]);
  tv[3] = b2 ? tv[2] : (b3 ? s : tv[3]); ti[3] = b2 ? ti[2] : (b3 ? idx : ti[3]);
  tv[2] = b1 ? tv[1] : (b2 ? s : tv[2]); ti[2] = b1 ? ti[1] : (b2 ? idx : ti[2]);
  tv[1] = b0 ? tv[0] : (b1 ? s : tv[1]); ti[1] = b0 ? ti[0] : (b1 ? idx : ti[1]);
  tv[0] = b0 ? s : tv[0];                ti[0] = b0 ? idx : ti[0];
}

// ---------------- Flash attention + top-4, 2 query rows per lane ----------------
// Grid (N/64, H, B) = 512 blocks, 256 threads. Thread t: qr=t>>3 handles rows
// l0+qr and l0+qr+32; qc=t&7 owns s-columns qc*8..qc*8+7 of each 64-key tile.
// No online max (logits ~N(0,1); max over 13M samples ~5.5 -> exp safe; verified
// R1 vs R3 absmax identical). Each Ks/Vs read feeds both rows (halves LDS wall).
// __launch_bounds__(256,1): R3's (256,2) capped VGPR at 128 -> scratch spills
// (5 GB FETCH). Budget 512 lets the ~190-reg working set stay in registers.
__global__ __launch_bounds__(256, 1) void attn_kernel(const float* __restrict__ qkv,
                                                      float* __restrict__ msg,
                                                      float* __restrict__ out_s,
                                                      float* __restrict__ out_i) {
  const int l0 = blockIdx.x * 64;
  const int h = blockIdx.y;
  const int b = blockIdx.z;
  const int t = threadIdx.x;
  const int qr = t >> 3, qc = t & 7;

  // chunk c of key-row ss stored at col (c + (ss>>3)) & 7 -> the 8 qc lanes hit
  // 8 distinct bank-quads (conflict-free); 8 qr groups broadcast (free).
  __shared__ float4 Ks[64][8];
  __shared__ float4 Vs[64][8];

  const size_t rs = 768;  // qkv row stride
  const float* qrow0 = qkv + ((size_t)(b * N_) + l0 + qr) * rs + h * DH_;
  const float* qrow1 = qrow0 + 32 * rs;
  float4 qa[8], qb[8];
  #pragma unroll
  for (int c = 0; c < 8; c++) {
    float4 v0 = ((const float4*)qrow0)[c];
    v0.x *= TEMP_; v0.y *= TEMP_; v0.z *= TEMP_; v0.w *= TEMP_;
    qa[c] = v0;
    float4 v1 = ((const float4*)qrow1)[c];
    v1.x *= TEMP_; v1.y *= TEMP_; v1.z *= TEMP_; v1.w *= TEMP_;
    qb[c] = v1;
  }
  float4 oa[8], ob[8];
  #pragma unroll
  for (int c = 0; c < 8; c++) {
    oa[c] = make_float4(0.f, 0.f, 0.f, 0.f);
    ob[c] = make_float4(0.f, 0.f, 0.f, 0.f);
  }
  float la = 0.f, lb = 0.f;
  float tva[4], tvb[4];
  int tia[4], tib[4];
  #pragma unroll
  for (int i = 0; i < 4; i++) {
    tva[i] = -INFINITY; tia[i] = 0x7fffffff;
    tvb[i] = -INFINITY; tib[i] = 0x7fffffff;
  }

  const float* kbase = qkv + (size_t)(b * N_) * rs + 256 + h * DH_;

  for (int s0 = 0; s0 < N_; s0 += 64) {
    __syncthreads();
    #pragma unroll
    for (int f0 = 0; f0 < 512; f0 += 256) {
      int f = f0 + t;
      int row = f >> 3, j = f & 7;
      int col = (j + (row >> 3)) & 7;
      const float* kp = kbase + (size_t)(s0 + row) * rs + j * 4;
      Ks[row][col] = *(const float4*)kp;
      Vs[row][col] = *(const float4*)(kp + 256);
    }
    __syncthreads();

    #pragma unroll
    for (int j = 0; j < 8; j++) {
      int ss = qc * 8 + j;
      float4 aa = {0, 0, 0, 0}, ab = {0, 0, 0, 0};
      #pragma unroll
      for (int c = 0; c < 8; c++) {
        float4 kv = Ks[ss][(c + qc) & 7];
        float4 q0 = qa[c];
        float4 q1 = qb[c];
        aa.x = fmaf(q0.x, kv.x, aa.x); aa.y = fmaf(q0.y, kv.y, aa.y);
        aa.z = fmaf(q0.z, kv.z, aa.z); aa.w = fmaf(q0.w, kv.w, aa.w);
        ab.x = fmaf(q1.x, kv.x, ab.x); ab.y = fmaf(q1.y, kv.y, ab.y);
        ab.z = fmaf(q1.z, kv.z, ab.z); ab.w = fmaf(q1.w, kv.w, ab.w);
      }
      float sa = (aa.x + aa.y) + (aa.z + aa.w);
      float sb = (ab.x + ab.y) + (ab.z + ab.w);
      int idx = s0 + ss;
      ins4(sa, idx, tva, tia);
      ins4(sb, idx, tvb, tib);
      float pa = __expf(sa);
      float pb = __expf(sb);
      la += pa;
      lb += pb;
      #pragma unroll
      for (int c = 0; c < 8; c++) {
        float4 vv = Vs[ss][(c + qc) & 7];
        oa[c].x = fmaf(pa, vv.x, oa[c].x); oa[c].y = fmaf(pa, vv.y, oa[c].y);
        oa[c].z = fmaf(pa, vv.z, oa[c].z); oa[c].w = fmaf(pa, vv.w, oa[c].w);
        ob[c].x = fmaf(pb, vv.x, ob[c].x); ob[c].y = fmaf(pb, vv.y, ob[c].y);
        ob[c].z = fmaf(pb, vv.z, ob[c].z); ob[c].w = fmaf(pb, vv.w, ob[c].w);
      }
    }
  }

  // ---- merge the 8 lanes of each query row (lanes contiguous: xor 1,2,4) ----
  la += __shfl_xor(la, 1); la += __shfl_xor(la, 2); la += __shfl_xor(la, 4);
  lb += __shfl_xor(lb, 1); lb += __shfl_xor(lb, 2); lb += __shfl_xor(lb, 4);
  #pragma unroll
  for (int d = 1; d <= 4; d <<= 1) {
    float ova[4], ovb[4];
    int oia[4], oib[4];
    #pragma unroll
    for (int r = 0; r < 4; r++) {
      ova[r] = __shfl_xor(tva[r], d); oia[r] = __shfl_xor(tia[r], d);
      ovb[r] = __shfl_xor(tvb[r], d); oib[r] = __shfl_xor(tib[r], d);
    }
    #pragma unroll
    for (int r = 0; r < 4; r++) {
      ins4_tie(ova[r], oia[r], tva, tia);
      ins4_tie(ovb[r], oib[r], tvb, tib);
    }
  }

  // ---- allreduce each O chunk across the 8 lanes; keep own chunk via cndmask ----
  float4 ra = {0, 0, 0, 0}, rb = {0, 0, 0, 0};
  #pragma unroll
  for (int c = 0; c < 8; c++) {
    float4 sa = oa[c], sb = ob[c];
    #pragma unroll
    for (int d = 1; d <= 4; d <<= 1) {
      sa.x += __shfl_xor(sa.x, d); sa.y += __shfl_xor(sa.y, d);
      sa.z += __shfl_xor(sa.z, d); sa.w += __shfl_xor(sa.w, d);
      sb.x += __shfl_xor(sb.x, d); sb.y += __shfl_xor(sb.y, d);
      sb.z += __shfl_xor(sb.z, d); sb.w += __shfl_xor(sb.w, d);
    }
    bool mine = (qc == c);
    ra.x = mine ? sa.x : ra.x; ra.y = mine ? sa.y : ra.y;
    ra.z = mine ? sa.z : ra.z; ra.w = mine ? sa.w : ra.w;
    rb.x = mine ? sb.x : rb.x; rb.y = mine ? sb.y : rb.y;
    rb.z = mine ? sb.z : rb.z; rb.w = mine ? sb.w : rb.w;
  }

  float linva = 1.0f / la, linvb = 1.0f / lb;
  ra.x *= linva; ra.y *= linva; ra.z *= linva; ra.w *= linva;
  rb.x *= linvb; rb.y *= linvb; rb.z *= linvb; rb.w *= linvb;

  float sca[4], scb[4];
  #pragma unroll
  for (int r = 0; r < 4; r++) {
    sca[r] = __expf(tva[r]) * linva;
    scb[r] = __expf(tvb[r]) * linvb;
    const float* vpa =
        qkv + ((size_t)(b * N_) + tia[r]) * rs + 512 + h * DH_ + qc * 4;
    float4 va = *(const float4*)vpa;
    ra.x = fmaf(-sca[r], va.x, ra.x); ra.y = fmaf(-sca[r], va.y, ra.y);
    ra.z = fmaf(-sca[r], va.z, ra.z); ra.w = fmaf(-sca[r], va.w, ra.w);
    const float* vpb =
        qkv + ((size_t)(b * N_) + tib[r]) * rs + 512 + h * DH_ + qc * 4;
    float4 vb = *(const float4*)vpb;
    rb.x = fmaf(-scb[r], vb.x, rb.x); rb.y = fmaf(-scb[r], vb.y, rb.y);
    rb.z = fmaf(-scb[r], vb.z, rb.z); rb.w = fmaf(-scb[r], vb.w, rb.w);
  }

  float* mpa = msg + ((size_t)(b * N_) + l0 + qr) * DIM_ + h * DH_ + qc * 4;
  *(float4*)mpa = ra;
  float* mpb = mpa + 32 * DIM_;
  *(float4*)mpb = rb;

  if (qc == 0) {
    size_t basea = ((size_t)(b * N_ + l0 + qr)) * TOPK_;
    size_t baseb = basea + 32 * TOPK_;
    #pragma unroll
    for (int r = 0; r < 4; r++) {
      out_s[(basea + r) * H_ + h] = sca[r];
      out_i[(basea + r) * H_ + h] = (float)tia[r];
      out_s[(baseb + r) * H_ + h] = scb[r];
      out_i[(baseb + r) * H_ + h] = (float)tib[r];
    }
  }
}

extern "C" void kernel_launch(void* const* d_in, const int* in_sizes, int n_in,
                              void* d_out, int out_size, void* d_ws, size_t ws_size,
                              hipStream_t stream) {
  const float* points = (const float*)d_in[0];
  const float* norm_gamma = (const float*)d_in[1];
  const float* norm_beta = (const float*)d_in[2];
  const float* w_qkv = (const float*)d_in[3];
  const float* w_proj = (const float*)d_in[4];
  const float* b_proj = (const float*)d_in[5];

  float* out0 = (float*)d_out;                       // message_flat (4096*256)
  float* out1 = out0 + (size_t)4096 * 256;           // topk_score (4096*4*8)
  float* out2 = out1 + (size_t)4096 * 4 * 8;         // topk_idx as float

  float* xn = (float*)d_ws;                          // 4096*256
  float* qkv = xn + (size_t)4096 * 256;              // 4096*768
  float* msg = qkv + (size_t)4096 * 768;             // 4096*256

  ln_kernel<<<1024, 256, 0, stream>>>(points, norm_gamma, norm_beta, xn);
  gemm_nt<false><<<dim3(64, 12), 256, 0, stream>>>(xn, w_qkv, qkv, nullptr,
                                                   nullptr, 256, 768);
  attn_kernel<<<dim3(N_ / 64, H_, B_), 256, 0, stream>>>(qkv, msg, out1, out2);
  gemm_nt<true><<<dim3(64, 4), 256, 0, stream>>>(msg, w_proj, out0, qkv + 512,
                                                 b_proj, 256, 256);
}

// Round 6
// 473.701 us; speedup vs baseline: 8.0618x; 1.1829x over previous
//
#include <hip/hip_runtime.h>
#include <math.h>

#define B_ 2
#define N_ 2048
#define H_ 8
#define DH_ 32
#define TOPK_ 4
#define EPS_ 1e-5f
#define TEMP_ 0.17677669529663687f  // 1/sqrt(32)

typedef __attribute__((ext_vector_type(8))) short short8;   // 8 bf16 = 4 VGPRs
typedef __attribute__((ext_vector_type(4))) float f32x4;

__device__ __forceinline__ unsigned short f2bf(float x) {  // RN-even
  unsigned u = __float_as_uint(x);
  u += 0x7FFF + ((u >> 16) & 1);
  return (unsigned short)(u >> 16);
}
__device__ __forceinline__ float bf2f(unsigned short h) {
  return __uint_as_float(((unsigned)h) << 16);
}

// Branch-free sorted top-6 insert, exact fp32 value + key. Strict > only:
// per-lane scan order is ascending key, so ties keep the incumbent (lower key)
// -> matches lax.top_k. Constant indices -> stays in registers.
__device__ __forceinline__ void ins6f(float v, int k, float tv[6], int ti[6]) {
  bool b0 = v > tv[0], b1 = v > tv[1], b2 = v > tv[2];
  bool b3 = v > tv[3], b4 = v > tv[4], b5 = v > tv[5];
  tv[5] = b4 ? tv[4] : (b5 ? v : tv[5]); ti[5] = b4 ? ti[4] : (b5 ? k : ti[5]);
  tv[4] = b3 ? tv[3] : (b4 ? v : tv[4]); ti[4] = b3 ? ti[3] : (b4 ? k : ti[4]);
  tv[3] = b2 ? tv[2] : (b3 ? v : tv[3]); ti[3] = b2 ? ti[2] : (b3 ? k : ti[3]);
  tv[2] = b1 ? tv[1] : (b2 ? v : tv[2]); ti[2] = b1 ? ti[1] : (b2 ? k : ti[2]);
  tv[1] = b0 ? tv[0] : (b1 ? v : tv[1]); ti[1] = b0 ? ti[0] : (b1 ? k : ti[1]);
  tv[0] = b0 ? v : tv[0];                ti[0] = b0 ? k : ti[0];
}

// Tie-aware top-6 insert for cross-lane merges (lists not in key order).
__device__ __forceinline__ void ins6ft(float v, int k, float tv[6], int ti[6]) {
  bool b0 = (v > tv[0]) || (v == tv[0] && k < ti[0]);
  bool b1 = (v > tv[1]) || (v == tv[1] && k < ti[1]);
  bool b2 = (v > tv[2]) || (v == tv[2] && k < ti[2]);
  bool b3 = (v > tv[3]) || (v == tv[3] && k < ti[3]);
  bool b4 = (v > tv[4]) || (v == tv[4] && k < ti[4]);
  bool b5 = (v > tv[5]) || (v == tv[5] && k < ti[5]);
  tv[5] = b4 ? tv[4] : (b5 ? v : tv[5]); ti[5] = b4 ? ti[4] : (b5 ? k : ti[5]);
  tv[4] = b3 ? tv[3] : (b4 ? v : tv[4]); ti[4] = b3 ? ti[3] : (b4 ? k : ti[4]);
  tv[3] = b2 ? tv[2] : (b3 ? v : tv[3]); ti[3] = b2 ? ti[2] : (b3 ? k : ti[3]);
  tv[2] = b1 ? tv[1] : (b2 ? v : tv[2]); ti[2] = b1 ? ti[1] : (b2 ? k : ti[2]);
  tv[1] = b0 ? tv[0] : (b1 ? v : tv[1]); ti[1] = b0 ? ti[0] : (b1 ? k : ti[1]);
  tv[0] = b0 ? v : tv[0];                ti[0] = b0 ? k : ti[0];
}

// top-4 insert carrying (exact score, key, dekker value); ties -> lower key.
__device__ __forceinline__ void ins4d(float s, int idx, float dv,
                                      float tv[4], int ti[4], float td[4]) {
  bool b0 = (s > tv[0]) || (s == tv[0] && idx < ti[0]);
  bool b1 = (s > tv[1]) || (s == tv[1] && idx < ti[1]);
  bool b2 = (s > tv[2]) || (s == tv[2] && idx < ti[2]);
  bool b3 = (s > tv[3]) || (s == tv[3] && idx < ti[3]);
  tv[3] = b2 ? tv[2] : (b3 ? s : tv[3]); ti[3] = b2 ? ti[2] : (b3 ? idx : ti[3]); td[3] = b2 ? td[2] : (b3 ? dv : td[3]);
  tv[2] = b1 ? tv[1] : (b2 ? s : tv[2]); ti[2] = b1 ? ti[1] : (b2 ? idx : ti[2]); td[2] = b1 ? td[1] : (b2 ? dv : td[2]);
  tv[1] = b0 ? tv[0] : (b1 ? s : tv[1]); ti[1] = b0 ? ti[0] : (b1 ? idx : ti[1]); td[1] = b0 ? td[0] : (b1 ? dv : td[1]);
  tv[0] = b0 ? s : tv[0];                ti[0] = b0 ? idx : ti[0];                td[0] = b0 ? dv : td[0];
}

// ---------------- LayerNorm ----------------
__global__ __launch_bounds__(256) void ln_kernel(const float* __restrict__ x,
                                                 const float* __restrict__ gamma,
                                                 const float* __restrict__ beta,
                                                 float* __restrict__ xn) {
  int w = threadIdx.x >> 6, ld = threadIdx.x & 63;
  int row = blockIdx.x * 4 + w;
  const float4* xr = (const float4*)(x + (size_t)row * 256);
  float4 v = xr[ld];
  float s = v.x + v.y + v.z + v.w;
  float ss = v.x * v.x + v.y * v.y + v.z * v.z + v.w * v.w;
  #pragma unroll
  for (int off = 1; off < 64; off <<= 1) {
    s += __shfl_xor(s, off);
    ss += __shfl_xor(ss, off);
  }
  float mu = s * (1.0f / 256.0f);
  float var = ss * (1.0f / 256.0f) - mu * mu;
  float rstd = rsqrtf(var + EPS_);
  float4 g = ((const float4*)gamma)[ld];
  float4 bt = ((const float4*)beta)[ld];
  float4 o;
  o.x = (v.x - mu) * rstd * g.x + bt.x;
  o.y = (v.y - mu) * rstd * g.y + bt.y;
  o.z = (v.z - mu) * rstd * g.z + bt.z;
  o.w = (v.w - mu) * rstd * g.w + bt.w;
  ((float4*)(xn + (size_t)row * 256))[ld] = o;
}

// ---------------- fp32 tiled GEMM (NT). SPLIT: also emit bf16 hi/lo copies ----
template <bool PROJ, bool SPLIT>
__global__ __launch_bounds__(256) void gemm_nt(const float* __restrict__ A,
                                               const float* __restrict__ Bm,
                                               float* __restrict__ C,
                                               const float* __restrict__ vres,
                                               const float* __restrict__ bias,
                                               unsigned short* __restrict__ qh_out,
                                               unsigned short* __restrict__ ql_out,
                                               int K, int ldc) {
  __shared__ float As[32][64];
  __shared__ float Bs[32][64];
  int m0 = blockIdx.x * 64, n0 = blockIdx.y * 64;
  int t = threadIdx.x;
  int tm = t & 15, tn = t >> 4;
  float acc[4][4] = {};
  for (int k0 = 0; k0 < K; k0 += 32) {
    __syncthreads();
    for (int f = t; f < 512; f += 256) {
      int row = f >> 3, j = f & 7;
      float4 a = *(const float4*)(A + (size_t)(m0 + row) * K + k0 + j * 4);
      As[j * 4 + 0][row] = a.x; As[j * 4 + 1][row] = a.y;
      As[j * 4 + 2][row] = a.z; As[j * 4 + 3][row] = a.w;
      float4 b = *(const float4*)(Bm + (size_t)(n0 + row) * K + k0 + j * 4);
      Bs[j * 4 + 0][row] = b.x; Bs[j * 4 + 1][row] = b.y;
      Bs[j * 4 + 2][row] = b.z; Bs[j * 4 + 3][row] = b.w;
    }
    __syncthreads();
    #pragma unroll
    for (int k = 0; k < 32; k++) {
      float4 a = *(const float4*)&As[k][tm * 4];
      float4 b = *(const float4*)&Bs[k][tn * 4];
      float av[4] = {a.x, a.y, a.z, a.w};
      float bv[4] = {b.x, b.y, b.z, b.w};
      #pragma unroll
      for (int i = 0; i < 4; i++)
        #pragma unroll
        for (int j = 0; j < 4; j++)
          acc[i][j] = fmaf(av[i], bv[j], acc[i][j]);
    }
  }
  #pragma unroll
  for (int i = 0; i < 4; i++) {
    int m = m0 + tm * 4 + i;
    int n = n0 + tn * 4;
    float4 r = {acc[i][0], acc[i][1], acc[i][2], acc[i][3]};
    if (PROJ) {
      float4 vr = *(const float4*)(vres + (size_t)m * 768 + n);
      float4 bb = *(const float4*)(bias + n);
      r.x += vr.x + bb.x; r.y += vr.y + bb.y;
      r.z += vr.z + bb.z; r.w += vr.w + bb.w;
    }
    *(float4*)(C + (size_t)m * ldc + n) = r;
    if (SPLIT) {
      ushort4 hi, lo;
      hi.x = f2bf(r.x); lo.x = f2bf(r.x - bf2f(hi.x));
      hi.y = f2bf(r.y); lo.y = f2bf(r.y - bf2f(hi.y));
      hi.z = f2bf(r.z); lo.z = f2bf(r.z - bf2f(hi.z));
      hi.w = f2bf(r.w); lo.w = f2bf(r.w - bf2f(hi.w));
      *(ushort4*)(qh_out + (size_t)m * ldc + n) = hi;
      *(ushort4*)(ql_out + (size_t)m * ldc + n) = lo;
    }
  }
}

// ---------------- V transpose to bf16: vt[bh][dim][key] ----------------
__global__ __launch_bounds__(256) void vt_kernel(const float* __restrict__ qkv,
                                                 unsigned short* __restrict__ vt) {
  int s0 = blockIdx.x * 64;
  int bh = blockIdx.y;
  int b = bh >> 3, h = bh & 7;
  int t = threadIdx.x;
  __shared__ __align__(16) unsigned short T[32][72];
  int key = t >> 2, c4 = t & 3;
  const float* vp = qkv + ((size_t)(b * N_) + s0 + key) * 768 + 512 + h * DH_ + c4 * 8;
  float4 a = *(const float4*)vp;
  float4 bb = *(const float4*)(vp + 4);
  T[c4 * 8 + 0][key] = f2bf(a.x);  T[c4 * 8 + 1][key] = f2bf(a.y);
  T[c4 * 8 + 2][key] = f2bf(a.z);  T[c4 * 8 + 3][key] = f2bf(a.w);
  T[c4 * 8 + 4][key] = f2bf(bb.x); T[c4 * 8 + 5][key] = f2bf(bb.y);
  T[c4 * 8 + 6][key] = f2bf(bb.z); T[c4 * 8 + 7][key] = f2bf(bb.w);
  __syncthreads();
  int dim = t >> 3, kc = t & 7;
  short8 v = *(const short8*)(&T[dim][kc * 8]);
  *(short8*)(vt + ((size_t)bh * 32 + dim) * 2048 + s0 + kc * 8) = v;
}

// ---------------- MFMA flash attention + exact-fp32 candidate tracking ----------
// Grid (64,8,2), block 128 = 2 waves; wave handles 16 Q-rows.
// QK: 3-term Dekker bf16 MFMA (logit err ~2e-5 abs). PV: bf16 P x bf16 V MFMA.
// Candidates: per-(lane,row) top-6 by EXACT fp32 Dekker logit (value+key) —
// R5's bf16-packed tracking dropped true-4th on bf16 ties (~10 rows/bench).
__global__ __launch_bounds__(128) void attn_mfma(const unsigned short* __restrict__ qkvh,
                                                 const unsigned short* __restrict__ qkvl,
                                                 const unsigned short* __restrict__ vt,
                                                 float* __restrict__ ows,
                                                 float* __restrict__ lws,
                                                 float* __restrict__ candv,
                                                 int* __restrict__ candi) {
  const int h = blockIdx.y, b = blockIdx.z;
  const int bh = b * H_ + h;
  const int w = threadIdx.x >> 6;
  const int lane = threadIdx.x & 63;
  const int quad = lane >> 4, m16 = lane & 15;
  const int rowbase = blockIdx.x * 32 + w * 16;
  const int t = threadIdx.x;

  __shared__ __align__(16) unsigned short KsH[64][40];
  __shared__ __align__(16) unsigned short KsL[64][40];
  __shared__ __align__(16) unsigned short Ps[2][16][72];  // per-wave P tile

  // Q A-frags: A[m=lane&15][k=quad*8+j]
  const size_t qoff = ((size_t)(b * N_) + rowbase + m16) * 768 + h * DH_ + quad * 8;
  short8 qh = *(const short8*)(qkvh + qoff);
  short8 ql = *(const short8*)(qkvl + qoff);

  f32x4 o0 = {0.f, 0.f, 0.f, 0.f}, o1 = {0.f, 0.f, 0.f, 0.f};
  float lp[4] = {0.f, 0.f, 0.f, 0.f};
  float tv6[4][6];
  int ti6[4][6];
  #pragma unroll
  for (int r = 0; r < 4; r++)
    #pragma unroll
    for (int s = 0; s < 6; s++) { tv6[r][s] = -INFINITY; ti6[r][s] = 0x7fffffff; }

  const unsigned short* vbase = vt + (size_t)bh * 32 * 2048;

  for (int s0 = 0; s0 < N_; s0 += 64) {
    __syncthreads();
    #pragma unroll
    for (int i = 0; i < 4; i++) {
      int f = t + i * 128;
      int key = (f >> 2) & 63, chunk = f & 3;
      const unsigned short* src = (i < 2) ? qkvh : qkvl;
      short8 v = *(const short8*)(src + ((size_t)(b * N_) + s0 + key) * 768 + 256 +
                                  h * DH_ + chunk * 8);
      unsigned short* dst = (i < 2) ? &KsH[0][0] : &KsL[0][0];
      *(short8*)(dst + key * 40 + chunk * 8) = v;
    }
    __syncthreads();

    #pragma unroll
    for (int ct = 0; ct < 4; ct++) {
      short8 kh = *(const short8*)(&KsH[ct * 16 + m16][quad * 8]);
      short8 kl = *(const short8*)(&KsL[ct * 16 + m16][quad * 8]);
      f32x4 acc = {0.f, 0.f, 0.f, 0.f};
      acc = __builtin_amdgcn_mfma_f32_16x16x32_bf16(qh, kh, acc, 0, 0, 0);
      acc = __builtin_amdgcn_mfma_f32_16x16x32_bf16(qh, kl, acc, 0, 0, 0);
      acc = __builtin_amdgcn_mfma_f32_16x16x32_bf16(ql, kh, acc, 0, 0, 0);
      int key = s0 + ct * 16 + m16;  // ascending per lane -> strict-> insert OK
      #pragma unroll
      for (int r = 0; r < 4; r++) {
        float p = __expf(TEMP_ * acc[r]);
        lp[r] += p;
        Ps[w][quad * 4 + r][ct * 16 + m16] = f2bf(p);  // C-layout -> A-layout
        ins6f(acc[r], key, tv6[r], ti6[r]);
      }
    }
    // PV: A = P (rows x 32 keys), B = Vt (keys x 16 dims); same-wave LDS in order
    #pragma unroll
    for (int f = 0; f < 2; f++) {
      short8 pa = *(const short8*)(&Ps[w][m16][f * 32 + quad * 8]);
      short8 v0 = *(const short8*)(vbase + (size_t)m16 * 2048 + s0 + f * 32 + quad * 8);
      short8 v1 = *(const short8*)(vbase + (size_t)(16 + m16) * 2048 + s0 + f * 32 + quad * 8);
      o0 = __builtin_amdgcn_mfma_f32_16x16x32_bf16(pa, v0, o0, 0, 0, 0);
      o1 = __builtin_amdgcn_mfma_f32_16x16x32_bf16(pa, v1, o1, 0, 0, 0);
    }
  }

  // reduce l and merge candidates across the 16 col-lanes (xor 1,2,4,8)
  #pragma unroll
  for (int d = 1; d <= 8; d <<= 1) {
    #pragma unroll
    for (int r = 0; r < 4; r++) {
      lp[r] += __shfl_xor(lp[r], d);
      float fv[6];
      int fk[6];
      #pragma unroll
      for (int s = 0; s < 6; s++) {
        fv[s] = __shfl_xor(tv6[r][s], d);
        fk[s] = __shfl_xor(ti6[r][s], d);
      }
      #pragma unroll
      for (int s = 0; s < 6; s++) ins6ft(fv[s], fk[s], tv6[r], ti6[r]);
    }
  }

  #pragma unroll
  for (int r = 0; r < 4; r++) {
    int row = rowbase + quad * 4 + r;
    size_t rg = (size_t)bh * N_ + row;
    ows[rg * 32 + m16] = o0[r];
    ows[rg * 32 + 16 + m16] = o1[r];
    if (m16 == 0) {
      lws[rg] = lp[r];
      #pragma unroll
      for (int s = 0; s < 6; s++) {
        candv[rg * 6 + s] = tv6[r][s];
        candi[rg * 6 + s] = ti6[r][s];
      }
    }
  }
}

// ---------------- Exact rescore of candidates + finalize message ----------------
__global__ __launch_bounds__(64) void finalize_kernel(const float* __restrict__ qkv,
                                                      const float* __restrict__ ows,
                                                      const float* __restrict__ lws,
                                                      const float* __restrict__ candv,
                                                      const int* __restrict__ candi,
                                                      float* __restrict__ msg,
                                                      float* __restrict__ out_s,
                                                      float* __restrict__ out_i) {
  int bid = blockIdx.x;
  int bh = bid >> 7, rgi = bid & 127;
  int b = bh >> 3, h = bh & 7;
  int lane = threadIdx.x & 63;
  int m16 = lane & 15, g = lane >> 4;
  int row = rgi * 16 + m16;
  size_t rg = (size_t)bh * N_ + row;

  const float* qp = qkv + ((size_t)(b * N_) + row) * 768 + h * DH_;
  float sv[2], sd[2];
  int si[2];
  #pragma unroll
  for (int c = 0; c < 2; c++) {
    int ci = g * 2 + c;
    int cidx = rg * 6 + (ci < 6 ? ci : 0);
    int key = candi[cidx];
    float dv = candv[cidx];
    bool valid = (ci < 6) && (key < N_);
    int kk = valid ? key : 0;
    const float* kp = qkv + ((size_t)(b * N_) + kk) * 768 + 256 + h * DH_;
    float acc = 0.f;
    #pragma unroll
    for (int d2 = 0; d2 < 8; d2++) {
      float4 qv = *(const float4*)(qp + d2 * 4);
      float4 kv = *(const float4*)(kp + d2 * 4);
      acc += qv.x * kv.x + qv.y * kv.y + qv.z * kv.z + qv.w * kv.w;
    }
    sv[c] = valid ? TEMP_ * acc : -INFINITY;
    si[c] = valid ? key : 0x7fffffff;
    sd[c] = dv;
  }
  // gather all 8 (2 garbage) via butterfly
  float av[8], ad[8];
  int ai[8];
  av[0] = sv[0]; av[1] = sv[1]; ai[0] = si[0]; ai[1] = si[1]; ad[0] = sd[0]; ad[1] = sd[1];
  #pragma unroll
  for (int c = 0; c < 2; c++) {
    av[2 + c] = __shfl_xor(av[c], 16); ai[2 + c] = __shfl_xor(ai[c], 16);
    ad[2 + c] = __shfl_xor(ad[c], 16);
  }
  #pragma unroll
  for (int c = 0; c < 4; c++) {
    av[4 + c] = __shfl_xor(av[c], 32); ai[4 + c] = __shfl_xor(ai[c], 32);
    ad[4 + c] = __shfl_xor(ad[c], 32);
  }
  float tv[4] = {-INFINITY, -INFINITY, -INFINITY, -INFINITY};
  int ti[4] = {0x7fffffff, 0x7fffffff, 0x7fffffff, 0x7fffffff};
  float td[4] = {0, 0, 0, 0};
  #pragma unroll
  for (int c = 0; c < 8; c++) ins4d(av[c], ai[c], ad[c], tv, ti, td);

  float l = lws[rg];
  float linv = 1.0f / l;
  float sc[4], sub[4];
  #pragma unroll
  for (int r = 0; r < 4; r++) {
    sc[r] = __expf(tv[r]) * linv;  // exact score output
    // EXACT bf16 p the PV MFMA consumed: identical expression & input as hot loop
    sub[r] = bf2f(f2bf(__expf(TEMP_ * td[r]))) * linv;
  }

  float oc[8];
  #pragma unroll
  for (int d2 = 0; d2 < 8; d2++) oc[d2] = ows[rg * 32 + g * 8 + d2] * linv;
  #pragma unroll
  for (int r = 0; r < 4; r++) {
    const float* vp = qkv + ((size_t)(b * N_) + ti[r]) * 768 + 512 + h * DH_ + g * 8;
    #pragma unroll
    for (int d2 = 0; d2 < 8; d2++) oc[d2] = fmaf(-sub[r], vp[d2], oc[d2]);
  }
  float* mp = msg + ((size_t)(b * N_) + row) * 256 + h * DH_ + g * 8;
  #pragma unroll
  for (int d2 = 0; d2 < 8; d2++) mp[d2] = oc[d2];

  if (g == 0) {
    size_t base = ((size_t)(b * N_) + row) * TOPK_;
    #pragma unroll
    for (int r = 0; r < 4; r++) {
      out_s[(base + r) * H_ + h] = sc[r];
      out_i[(base + r) * H_ + h] = (float)ti[r];
    }
  }
}

extern "C" void kernel_launch(void* const* d_in, const int* in_sizes, int n_in,
                              void* d_out, int out_size, void* d_ws, size_t ws_size,
                              hipStream_t stream) {
  const float* points = (const float*)d_in[0];
  const float* norm_gamma = (const float*)d_in[1];
  const float* norm_beta = (const float*)d_in[2];
  const float* w_qkv = (const float*)d_in[3];
  const float* w_proj = (const float*)d_in[4];
  const float* b_proj = (const float*)d_in[5];

  float* out0 = (float*)d_out;
  float* out1 = out0 + (size_t)4096 * 256;
  float* out2 = out1 + (size_t)4096 * 4 * 8;

  float* xn = (float*)d_ws;                          // 4096*256
  float* qkv = xn + (size_t)1048576;                 // 4096*768
  float* msg = qkv + (size_t)3145728;                // 4096*256
  float* ows = msg + (size_t)1048576;                // 16*2048*32
  float* lws = ows + (size_t)1048576;                // 16*2048
  float* candv = lws + 32768;                        // 16*2048*6
  int* candi = (int*)(candv + 196608);               // 16*2048*6
  unsigned short* qkvh = (unsigned short*)(candi + 196608);  // 4096*768
  unsigned short* qkvl = qkvh + (size_t)3145728;
  unsigned short* vt = qkvl + (size_t)3145728;       // 16*32*2048

  ln_kernel<<<1024, 256, 0, stream>>>(points, norm_gamma, norm_beta, xn);
  gemm_nt<false, true><<<dim3(64, 12), 256, 0, stream>>>(
      xn, w_qkv, qkv, nullptr, nullptr, qkvh, qkvl, 256, 768);
  vt_kernel<<<dim3(32, 16), 256, 0, stream>>>(qkv, vt);
  attn_mfma<<<dim3(64, H_, B_), 128, 0, stream>>>(qkvh, qkvl, vt, ows, lws,
                                                  candv, candi);
  finalize_kernel<<<2048, 64, 0, stream>>>(qkv, ows, lws, candv, candi, msg,
                                           out1, out2);
  gemm_nt<true, false><<<dim3(64, 4), 256, 0, stream>>>(
      msg, w_proj, out0, qkv + 512, b_proj, nullptr, nullptr, 256, 256);
}